// Round 1
// baseline (607.273 us; speedup 1.0000x reference)
//
#include <hip/hip_runtime.h>
#include <hip/hip_bf16.h>
#include <stdint.h>

#define NR 8192   // rows (N)
#define ND 1024   // feature dim (D)

typedef __attribute__((ext_vector_type(8))) short bf16x8;  // 8 bf16 = 4 VGPR
typedef __attribute__((ext_vector_type(4))) float f32x4;   // MFMA C/D

static __device__ __forceinline__ uint16_t f2bf(float f) {
  union { __hip_bfloat16 h; uint16_t u; } cv;
  cv.h = __float2bfloat16(f);
  return cv.u;
}

// ---------------- kernel 1: row L2 norm -> normalized bf16 ----------------
__global__ void k_norm(const float* __restrict__ X, uint16_t* __restrict__ Xn) {
  const int row = blockIdx.x;
  const int t = threadIdx.x;                    // 256 threads, 4 floats each
  const float4 v = reinterpret_cast<const float4*>(X + (size_t)row * ND)[t];
  float ss = v.x * v.x + v.y * v.y + v.z * v.z + v.w * v.w;
#pragma unroll
  for (int m = 1; m < 64; m <<= 1) ss += __shfl_xor(ss, m, 64);
  __shared__ float sred[4];
  if ((t & 63) == 0) sred[t >> 6] = ss;
  __syncthreads();
  const float tot = sred[0] + sred[1] + sred[2] + sred[3];
  const float inv = 1.0f / fmaxf(sqrtf(tot), 1e-12f);
  ushort4 o;
  o.x = f2bf(v.x * inv); o.y = f2bf(v.y * inv);
  o.z = f2bf(v.z * inv); o.w = f2bf(v.w * inv);
  reinterpret_cast<ushort4*>(Xn + (size_t)row * ND)[t] = o;
}

// ------------- kernel 1b: feats [NR][ND] f32 -> featsT [ND][NR] bf16 -------------
__global__ void k_transpose(const float* __restrict__ X, uint16_t* __restrict__ XT) {
  __shared__ uint16_t tile[32][33];
  const int ntr = NR / 32;                     // 256 row-tiles
  const int bx = blockIdx.x % ntr;             // row-tile of X
  const int by = blockIdx.x / ntr;             // col(dim)-tile of X
  const int r0 = bx * 32, d0 = by * 32;
  const int t = threadIdx.x;                   // 256
  const int rr = t >> 3, cc = (t & 7) * 4;
  const float4 v = *reinterpret_cast<const float4*>(&X[(size_t)(r0 + rr) * ND + d0 + cc]);
  tile[cc + 0][rr] = f2bf(v.x);
  tile[cc + 1][rr] = f2bf(v.y);
  tile[cc + 2][rr] = f2bf(v.z);
  tile[cc + 3][rr] = f2bf(v.w);
  __syncthreads();
  ushort4 o;
  o.x = tile[rr][cc + 0]; o.y = tile[rr][cc + 1];
  o.z = tile[rr][cc + 2]; o.w = tile[rr][cc + 3];
  *reinterpret_cast<ushort4*>(&XT[(size_t)(d0 + rr) * NR + r0 + cc]) = o;
}

// ---------------- BT GEMM: C[m][n] = sum_k A[m][k]*B[n][k] ----------------
// EPI==0: sims epilogue (exp, zero diag, write E fp32, per-block row partial sums)
// EPI==1: plain fp32 store
template <int EPI>
__global__ __launch_bounds__(256, 2) void k_gemm_bt(
    const uint16_t* __restrict__ A, int lda,
    const uint16_t* __restrict__ B, int ldb,
    int N, int K,
    float* __restrict__ C, int ldc,
    float* __restrict__ partials) {
  constexpr int BM = 128, BN = 128, BK = 32;
  __shared__ uint16_t sA[2][BM * BK];
  __shared__ uint16_t sB[2][BN * BK];
  __shared__ float sPart[2][BM];

  const int tid = threadIdx.x;
  const int wid = tid >> 6;
  const int lane = tid & 63;

  // XCD-aware swizzle (grid divisible by 8)
  const int nbx = N / BN;
  const int nwg = gridDim.x;
  const int cpx = nwg >> 3;
  const int b = blockIdx.x;
  const int swz = (b & 7) * cpx + (b >> 3);
  const int by = swz / nbx, bx = swz % nbx;
  const int row0 = by * BM, col0 = bx * BN;

  f32x4 acc[4][4] = {};

  auto stage = [&](int buf, int kt) {
    const int k0 = kt * BK;
#pragma unroll
    for (int c = 0; c < 2; ++c) {
      const int idx = c * 256 + tid;
      const int r = idx >> 2;             // row within tile
      const int col = (idx & 3) * 8;      // 8 bf16 = 16 B per lane
      const uint16_t* ga = A + (size_t)(row0 + r) * lda + k0 + col;
      const uint16_t* gb = B + (size_t)(col0 + r) * ldb + k0 + col;
      uint16_t* la = &sA[buf][(c * 256 + (wid << 6)) * 8];  // wave-uniform base
      uint16_t* lb = &sB[buf][(c * 256 + (wid << 6)) * 8];
      __builtin_amdgcn_global_load_lds((const __attribute__((address_space(1))) void*)ga,
                                       (__attribute__((address_space(3))) void*)la, 16, 0, 0);
      __builtin_amdgcn_global_load_lds((const __attribute__((address_space(1))) void*)gb,
                                       (__attribute__((address_space(3))) void*)lb, 16, 0, 0);
    }
  };

  const int wr = (wid >> 1) * 64;   // wave's 64x64 quadrant
  const int wc = (wid & 1) * 64;
  const int fr = lane & 15;
  const int kcol = (lane >> 4) * 8;

  const int nk = K / BK;
  int cur = 0;
  stage(0, 0);
  __syncthreads();

  for (int t = 0; t < nk; ++t) {
    if (t + 1 < nk) stage(cur ^ 1, t + 1);
    bf16x8 af[4], bfr[4];
#pragma unroll
    for (int i = 0; i < 4; ++i) {
      af[i]  = *reinterpret_cast<const bf16x8*>(&sA[cur][(wr + i * 16 + fr) * BK + kcol]);
      bfr[i] = *reinterpret_cast<const bf16x8*>(&sB[cur][(wc + i * 16 + fr) * BK + kcol]);
    }
#pragma unroll
    for (int i = 0; i < 4; ++i)
#pragma unroll
      for (int j = 0; j < 4; ++j)
        acc[i][j] = __builtin_amdgcn_mfma_f32_16x16x32_bf16(af[i], bfr[j], acc[i][j], 0, 0, 0);
    __syncthreads();   // drains vmcnt (stage done) + all LDS reads done
    cur ^= 1;
  }

  const int r0f = (lane >> 4) * 4;  // C/D: row=(lane>>4)*4+reg, col=lane&15
  const int c0f = lane & 15;

  if constexpr (EPI == 0) {
    float rp[4][4];
#pragma unroll
    for (int i = 0; i < 4; ++i)
#pragma unroll
      for (int e = 0; e < 4; ++e) rp[i][e] = 0.0f;
#pragma unroll
    for (int i = 0; i < 4; ++i) {
#pragma unroll
      for (int j = 0; j < 4; ++j) {
#pragma unroll
        for (int e = 0; e < 4; ++e) {
          const int grow = row0 + wr + i * 16 + r0f + e;
          const int gcol = col0 + wc + j * 16 + c0f;
          const float ev = (grow == gcol) ? 0.0f : __expf(acc[i][j][e]);
          C[(size_t)grow * ldc + gcol] = ev;
          rp[i][e] += ev;
        }
      }
    }
    // reduce across the 16 column-lanes of each row group
#pragma unroll
    for (int m = 1; m <= 8; m <<= 1)
#pragma unroll
      for (int i = 0; i < 4; ++i)
#pragma unroll
        for (int e = 0; e < 4; ++e) rp[i][e] += __shfl_xor(rp[i][e], m, 64);
    if (c0f == 0) {
#pragma unroll
      for (int i = 0; i < 4; ++i)
#pragma unroll
        for (int e = 0; e < 4; ++e) sPart[wid & 1][wr + i * 16 + r0f + e] = rp[i][e];
    }
    __syncthreads();
    if (tid < BM) partials[(size_t)bx * NR + row0 + tid] = sPart[0][tid] + sPart[1][tid];
  } else {
#pragma unroll
    for (int i = 0; i < 4; ++i)
#pragma unroll
      for (int j = 0; j < 4; ++j)
#pragma unroll
        for (int e = 0; e < 4; ++e)
          C[(size_t)(row0 + wr + i * 16 + r0f + e) * ldc + col0 + wc + j * 16 + c0f] =
              acc[i][j][e];
  }
}

// ---------------- rowsum: reduce 64 column-block partials ----------------
__global__ void k_rowsum(const float* __restrict__ partials, float* __restrict__ rowsum,
                         int ncb) {
  const int r = blockIdx.x * blockDim.x + threadIdx.x;  // 8192 threads
  float s = 0.0f;
  for (int cb = 0; cb < ncb; ++cb) s += partials[(size_t)cb * NR + r];
  rowsum[r] = s;
}

// ------- scale: attn = E / rowsum (in place, fp32) + bf16 copy for PV -------
__global__ void k_scale(float* __restrict__ E, const float* __restrict__ rowsum,
                        uint16_t* __restrict__ attn_bf) {
  const size_t total = (size_t)NR * NR / 4;
  for (size_t i = (size_t)blockIdx.x * blockDim.x + threadIdx.x; i < total;
       i += (size_t)gridDim.x * blockDim.x) {
    const int row = (int)((i * 4) >> 13);     // /8192
    const float inv = 1.0f / rowsum[row];
    float4 v = reinterpret_cast<float4*>(E)[i];
    v.x *= inv; v.y *= inv; v.z *= inv; v.w *= inv;
    reinterpret_cast<float4*>(E)[i] = v;
    ushort4 o;
    o.x = f2bf(v.x); o.y = f2bf(v.y); o.z = f2bf(v.z); o.w = f2bf(v.w);
    reinterpret_cast<ushort4*>(attn_bf)[i] = o;
  }
}

extern "C" void kernel_launch(void* const* d_in, const int* in_sizes, int n_in,
                              void* d_out, int out_size, void* d_ws, size_t ws_size,
                              hipStream_t stream) {
  const float* X = (const float*)d_in[0];          // [8192][1024] fp32
  float* out = (float*)d_out;                       // [8192][1024] fp32
  float* attn = out + (size_t)NR * ND;              // [8192][8192] fp32

  // workspace layout
  char* ws = (char*)d_ws;
  const size_t off_Xn   = 0;                                  // 16 MB bf16 normalized
  const size_t off_XT   = off_Xn + (size_t)NR * ND * 2;       // 16 MB bf16 feats^T
  const size_t off_Abf  = off_XT + (size_t)ND * NR * 2;       // 128 MB bf16 attn
  const size_t off_part = off_Abf + (size_t)NR * NR * 2;      // 2 MB partials
  const size_t off_rs   = off_part + (size_t)64 * NR * 4;     // 32 KB rowsum
  const size_t needed   = off_rs + (size_t)NR * 4;
  if (ws_size < needed) return;  // workspace too small; fail loudly via validation

  uint16_t* Xn  = (uint16_t*)(ws + off_Xn);
  uint16_t* XT  = (uint16_t*)(ws + off_XT);
  uint16_t* Abf = (uint16_t*)(ws + off_Abf);
  float* partials = (float*)(ws + off_part);
  float* rowsum   = (float*)(ws + off_rs);

  k_norm<<<NR, 256, 0, stream>>>(X, Xn);
  k_transpose<<<(NR / 32) * (ND / 32), 256, 0, stream>>>(X, XT);
  // sims GEMM: E = exp(Xn·Xnᵀ), diag=0, row partial sums. grid 64x64=4096
  k_gemm_bt<0><<<(NR / 128) * (NR / 128), 256, 0, stream>>>(
      Xn, ND, Xn, ND, NR, ND, attn, NR, partials);
  k_rowsum<<<NR / 256, 256, 0, stream>>>(partials, rowsum, NR / 128);
  k_scale<<<2048, 256, 0, stream>>>(attn, rowsum, Abf);
  // PV GEMM: out = attn_bf16 · featsᵀ(bf16)ᵀ. grid 64x8=512
  k_gemm_bt<1><<<(NR / 128) * (ND / 128), 256, 0, stream>>>(
      Abf, NR, XT, NR, ND, NR, out, ND, nullptr);
}

// Round 2
// 414.974 us; speedup vs baseline: 1.4634x; 1.4634x over previous
//
#include <hip/hip_runtime.h>
#include <hip/hip_bf16.h>
#include <stdint.h>

#define NR 8192   // rows (N)
#define ND 1024   // feature dim (D)

typedef __attribute__((ext_vector_type(8))) short bf16x8;  // 8 bf16 = 4 VGPR
typedef __attribute__((ext_vector_type(4))) float f32x4;   // MFMA C/D
typedef __attribute__((ext_vector_type(8))) unsigned short u16x8;

static __device__ __forceinline__ uint16_t f2bf(float f) {
  union { __hip_bfloat16 h; uint16_t u; } cv;
  cv.h = __float2bfloat16(f);
  return cv.u;
}
static __device__ __forceinline__ float bf2f(uint16_t u) {
  union { uint32_t i; float f; } cv;
  cv.i = ((uint32_t)u) << 16;
  return cv.f;
}

// ---------------- kernel 1: row L2 norm -> normalized bf16 ----------------
__global__ void k_norm(const float* __restrict__ X, uint16_t* __restrict__ Xn) {
  const int row = blockIdx.x;
  const int t = threadIdx.x;                    // 256 threads, 4 floats each
  const float4 v = reinterpret_cast<const float4*>(X + (size_t)row * ND)[t];
  float ss = v.x * v.x + v.y * v.y + v.z * v.z + v.w * v.w;
#pragma unroll
  for (int m = 1; m < 64; m <<= 1) ss += __shfl_xor(ss, m, 64);
  __shared__ float sred[4];
  if ((t & 63) == 0) sred[t >> 6] = ss;
  __syncthreads();
  const float tot = sred[0] + sred[1] + sred[2] + sred[3];
  const float inv = 1.0f / fmaxf(sqrtf(tot), 1e-12f);
  ushort4 o;
  o.x = f2bf(v.x * inv); o.y = f2bf(v.y * inv);
  o.z = f2bf(v.z * inv); o.w = f2bf(v.w * inv);
  reinterpret_cast<ushort4*>(Xn + (size_t)row * ND)[t] = o;
}

// ------------- kernel 1b: feats [NR][ND] f32 -> featsT [ND][NR] bf16 -------------
__global__ void k_transpose(const float* __restrict__ X, uint16_t* __restrict__ XT) {
  __shared__ uint16_t tile[32][33];
  const int ntr = NR / 32;                     // 256 row-tiles
  const int bx = blockIdx.x % ntr;             // row-tile of X
  const int by = blockIdx.x / ntr;             // col(dim)-tile of X
  const int r0 = bx * 32, d0 = by * 32;
  const int t = threadIdx.x;                   // 256
  const int rr = t >> 3, cc = (t & 7) * 4;
  const float4 v = *reinterpret_cast<const float4*>(&X[(size_t)(r0 + rr) * ND + d0 + cc]);
  tile[cc + 0][rr] = f2bf(v.x);
  tile[cc + 1][rr] = f2bf(v.y);
  tile[cc + 2][rr] = f2bf(v.z);
  tile[cc + 3][rr] = f2bf(v.w);
  __syncthreads();
  ushort4 o;
  o.x = tile[rr][cc + 0]; o.y = tile[rr][cc + 1];
  o.z = tile[rr][cc + 2]; o.w = tile[rr][cc + 3];
  *reinterpret_cast<ushort4*>(&XT[(size_t)(d0 + rr) * NR + r0 + cc]) = o;
}

// ---------------- BT GEMM core: C[m][n] = sum_k A[m][k]*B[n][k] ----------------
// EPI==0: symmetric-sims epilogue — exp, diag zero, write bf16 E tile + mirrored
//         tile (rb<cb) + deterministic per-block row partial sums (both triangles)
// EPI==1: plain fp32 store (PV split-K partial)
template <int EPI>
__device__ __forceinline__ void gemm_core(
    const uint16_t* __restrict__ A, int lda,
    const uint16_t* __restrict__ B, int ldb,
    int K, int row0, int col0,
    float* __restrict__ C, int ldc,
    uint16_t* __restrict__ Eo, float* __restrict__ partials,
    int rb, int cb) {
  constexpr int BM = 128, BN = 128, BK = 32;
  __shared__ uint16_t sA[2][BM * BK];
  __shared__ uint16_t sB[2][BN * BK];
  __shared__ float sPart[2][BM];
  __shared__ float sPartT[2][BN];

  const int tid = threadIdx.x;
  const int wid = tid >> 6;
  const int lane = tid & 63;

  f32x4 acc[4][4] = {};

  auto stage = [&](int buf, int kt) {
    const int k0 = kt * BK;
#pragma unroll
    for (int c = 0; c < 2; ++c) {
      const int idx = c * 256 + tid;
      const int r = idx >> 2;             // row within tile
      const int col = (idx & 3) * 8;      // 8 bf16 = 16 B per lane
      const uint16_t* ga = A + (size_t)(row0 + r) * lda + k0 + col;
      const uint16_t* gb = B + (size_t)(col0 + r) * ldb + k0 + col;
      uint16_t* la = &sA[buf][(c * 256 + (wid << 6)) * 8];  // wave-uniform base
      uint16_t* lb = &sB[buf][(c * 256 + (wid << 6)) * 8];
      __builtin_amdgcn_global_load_lds((const __attribute__((address_space(1))) void*)ga,
                                       (__attribute__((address_space(3))) void*)la, 16, 0, 0);
      __builtin_amdgcn_global_load_lds((const __attribute__((address_space(1))) void*)gb,
                                       (__attribute__((address_space(3))) void*)lb, 16, 0, 0);
    }
  };

  const int wr = (wid >> 1) * 64;   // wave's 64x64 quadrant
  const int wc = (wid & 1) * 64;
  const int fr = lane & 15;
  const int kcol = (lane >> 4) * 8;

  const int nk = K / BK;
  int cur = 0;
  stage(0, 0);
  __syncthreads();

  for (int t = 0; t < nk; ++t) {
    if (t + 1 < nk) stage(cur ^ 1, t + 1);
    bf16x8 af[4], bfr[4];
#pragma unroll
    for (int i = 0; i < 4; ++i) {
      af[i]  = *reinterpret_cast<const bf16x8*>(&sA[cur][(wr + i * 16 + fr) * BK + kcol]);
      bfr[i] = *reinterpret_cast<const bf16x8*>(&sB[cur][(wc + i * 16 + fr) * BK + kcol]);
    }
#pragma unroll
    for (int i = 0; i < 4; ++i)
#pragma unroll
      for (int j = 0; j < 4; ++j)
        acc[i][j] = __builtin_amdgcn_mfma_f32_16x16x32_bf16(af[i], bfr[j], acc[i][j], 0, 0, 0);
    __syncthreads();   // drains vmcnt (stage done) + all LDS reads done
    cur ^= 1;
  }

  const int r0f = (lane >> 4) * 4;  // C/D: row=(lane>>4)*4+reg, col=lane&15
  const int c0f = lane & 15;

  if constexpr (EPI == 0) {
    const bool diag = (rb == cb);
    float rp[4][4];   // [i][e] row partial sums
    float rpT[4];     // [j]    col partial sums (mirror rows)
#pragma unroll
    for (int i = 0; i < 4; ++i)
#pragma unroll
      for (int e = 0; e < 4; ++e) rp[i][e] = 0.0f;
#pragma unroll
    for (int j = 0; j < 4; ++j) rpT[j] = 0.0f;

#pragma unroll
    for (int i = 0; i < 4; ++i) {
#pragma unroll
      for (int j = 0; j < 4; ++j) {
        ushort4 mpack;
#pragma unroll
        for (int e = 0; e < 4; ++e) {
          const int grow = row0 + wr + i * 16 + r0f + e;
          const int gcol = col0 + wc + j * 16 + c0f;
          const float ev = (grow == gcol) ? 0.0f : __expf(acc[i][j][e]);
          const uint16_t eb = f2bf(ev);
          const float evr = bf2f(eb);         // sum the ROUNDED value (rows sum to 1)
          Eo[(size_t)grow * NR + gcol] = eb;
          rp[i][e] += evr;
          rpT[j] += evr;
          ((uint16_t*)&mpack)[e] = eb;
        }
        if (!diag) {
          const int gcol = col0 + wc + j * 16 + c0f;
          const int growb = row0 + wr + i * 16 + r0f;   // e=0..3 contiguous -> 8B store
          *reinterpret_cast<ushort4*>(&Eo[(size_t)gcol * NR + growb]) = mpack;
        }
      }
    }
    // row partials: reduce across the 16 column-lanes (c0f)
#pragma unroll
    for (int m = 1; m <= 8; m <<= 1)
#pragma unroll
      for (int i = 0; i < 4; ++i)
#pragma unroll
        for (int e = 0; e < 4; ++e) rp[i][e] += __shfl_xor(rp[i][e], m, 64);
    if (c0f == 0) {
#pragma unroll
      for (int i = 0; i < 4; ++i)
#pragma unroll
        for (int e = 0; e < 4; ++e) sPart[wid & 1][wr + i * 16 + r0f + e] = rp[i][e];
    }
    // col partials: reduce across the 4 row-groups (lane>>4)
#pragma unroll
    for (int m = 16; m <= 32; m <<= 1)
#pragma unroll
      for (int j = 0; j < 4; ++j) rpT[j] += __shfl_xor(rpT[j], m, 64);
    if (lane < 16 && !diag) {
#pragma unroll
      for (int j = 0; j < 4; ++j) sPartT[wid >> 1][wc + j * 16 + lane] = rpT[j];
    }
    __syncthreads();
    if (tid < BM) {
      partials[(size_t)cb * NR + row0 + tid] = sPart[0][tid] + sPart[1][tid];
      if (!diag)
        partials[(size_t)rb * NR + col0 + tid] = sPartT[0][tid] + sPartT[1][tid];
    }
  } else {
#pragma unroll
    for (int i = 0; i < 4; ++i)
#pragma unroll
      for (int j = 0; j < 4; ++j)
#pragma unroll
        for (int e = 0; e < 4; ++e)
          C[(size_t)(row0 + wr + i * 16 + r0f + e) * ldc + col0 + wc + j * 16 + c0f] =
              acc[i][j][e];
  }
}

// sims GEMM over the upper triangle (rb<=cb), XCD-swizzled
__global__ __launch_bounds__(256, 2) void k_gemm_sym(
    const uint16_t* __restrict__ Xn, uint16_t* __restrict__ E,
    float* __restrict__ partials) {
  const int nwg = gridDim.x;            // 2080, divisible by 8
  const int cpx = nwg >> 3;
  const int b = blockIdx.x;
  const int swz = (b & 7) * cpx + (b >> 3);
  int rem = swz, rb = 0;
  while (rem >= 64 - rb) { rem -= 64 - rb; ++rb; }   // uniform scalar loop
  const int cb = rb + rem;
  gemm_core<0>(Xn, ND, Xn, ND, ND, rb * 128, cb * 128,
               nullptr, 0, E, partials, rb, cb);
}

// PV GEMM, split-K x2, plain fp32 partial output
__global__ __launch_bounds__(256, 4) void k_gemm_pv(
    const uint16_t* __restrict__ E, const uint16_t* __restrict__ XT,
    float* __restrict__ P) {
  const int nwg = gridDim.x;            // 1024
  const int cpx = nwg >> 3;
  const int b = blockIdx.x;
  const int swz = (b & 7) * cpx + (b >> 3);
  const int s = swz >> 9;               // K split
  const int t = swz & 511;
  const int by = t >> 3, bx = t & 7;    // 64 x 8 tiles
  gemm_core<1>(E + (size_t)s * 4096, NR, XT + (size_t)s * 4096, NR, 4096,
               by * 128, bx * 128, P + (size_t)s * NR * ND, ND,
               nullptr, nullptr, 0, 0);
}

// ---------------- rowsum: reduce 64 column-block partials ----------------
__global__ void k_rowsum(const float* __restrict__ partials, float* __restrict__ rowsum,
                         int ncb) {
  const int r = blockIdx.x * blockDim.x + threadIdx.x;  // 8192 threads
  float s = 0.0f;
  for (int cb = 0; cb < ncb; ++cb) s += partials[(size_t)cb * NR + r];
  rowsum[r] = s;
}

// ------- fixup: out = (P0 + P1) / rowsum -------
__global__ void k_fixup(const float4* __restrict__ P0, const float4* __restrict__ P1,
                        const float* __restrict__ rowsum, float4* __restrict__ out) {
  const size_t i = (size_t)blockIdx.x * blockDim.x + threadIdx.x;  // float4 units
  const int row = (int)(i >> 8);                                   // /(ND/4)
  const float inv = 1.0f / rowsum[row];
  const float4 a = P0[i], b = P1[i];
  float4 o;
  o.x = (a.x + b.x) * inv; o.y = (a.y + b.y) * inv;
  o.z = (a.z + b.z) * inv; o.w = (a.w + b.w) * inv;
  out[i] = o;
}

// ------- scale: attn(fp32, d_out) = E(bf16) / rowsum -------
__global__ void k_scale(const uint16_t* __restrict__ E, const float* __restrict__ rowsum,
                        float* __restrict__ attn) {
  const size_t total = (size_t)NR * NR / 8;
  for (size_t i = (size_t)blockIdx.x * blockDim.x + threadIdx.x; i < total;
       i += (size_t)gridDim.x * blockDim.x) {
    const int row = (int)(i >> 10);     // (i*8)/8192
    const float inv = 1.0f / rowsum[row];
    const u16x8 e = reinterpret_cast<const u16x8*>(E)[i];
    float4 o0, o1;
    o0.x = bf2f(e[0]) * inv; o0.y = bf2f(e[1]) * inv;
    o0.z = bf2f(e[2]) * inv; o0.w = bf2f(e[3]) * inv;
    o1.x = bf2f(e[4]) * inv; o1.y = bf2f(e[5]) * inv;
    o1.z = bf2f(e[6]) * inv; o1.w = bf2f(e[7]) * inv;
    reinterpret_cast<float4*>(attn)[2 * i + 0] = o0;
    reinterpret_cast<float4*>(attn)[2 * i + 1] = o1;
  }
}

extern "C" void kernel_launch(void* const* d_in, const int* in_sizes, int n_in,
                              void* d_out, int out_size, void* d_ws, size_t ws_size,
                              hipStream_t stream) {
  const float* X = (const float*)d_in[0];          // [8192][1024] fp32
  float* out = (float*)d_out;                       // [8192][1024] fp32
  float* attn = out + (size_t)NR * ND;              // [8192][8192] fp32

  // workspace layout
  char* ws = (char*)d_ws;
  const size_t off_Xn   = 0;                                  // 16 MB bf16 normalized
  const size_t off_XT   = off_Xn + (size_t)NR * ND * 2;       // 16 MB bf16 feats^T
  const size_t off_E    = off_XT + (size_t)ND * NR * 2;       // 128 MB bf16 unscaled exp
  const size_t off_part = off_E + (size_t)NR * NR * 2;        // 2 MB partials
  const size_t off_rs   = off_part + (size_t)64 * NR * 4;     // 32 KB rowsum
  const size_t needed   = off_rs + (size_t)NR * 4;
  if (ws_size < needed) return;

  uint16_t* Xn  = (uint16_t*)(ws + off_Xn);
  uint16_t* XT  = (uint16_t*)(ws + off_XT);
  uint16_t* E   = (uint16_t*)(ws + off_E);
  float* partials = (float*)(ws + off_part);
  float* rowsum   = (float*)(ws + off_rs);

  // PV split-K partials use the (not yet written) attn region of d_out as scratch
  float* P = attn;   // 2 x 8.4M floats << 67.1M float region

  k_norm<<<NR, 256, 0, stream>>>(X, Xn);
  k_transpose<<<(NR / 32) * (ND / 32), 256, 0, stream>>>(X, XT);
  // E = exp(Xn.Xn^T) bf16 (diag=0), upper triangle + mirror, row partials
  k_gemm_sym<<<2080, 256, 0, stream>>>(Xn, E, partials);
  k_rowsum<<<NR / 256, 256, 0, stream>>>(partials, rowsum, NR / 128);
  // P[s] = E[:, s*4096:(s+1)*4096] . feats-slice  (fp32 partials into d_out scratch)
  k_gemm_pv<<<1024, 256, 0, stream>>>(E, XT, P);
  // out = (P0+P1)/rowsum
  k_fixup<<<NR * ND / 4 / 256, 256, 0, stream>>>(
      (const float4*)P, (const float4*)(P + (size_t)NR * ND), rowsum, (float4*)out);
  // attn = E/rowsum (fully overwrites the scratch region)
  k_scale<<<2048, 256, 0, stream>>>(E, rowsum, attn);
}

// Round 3
// 397.775 us; speedup vs baseline: 1.5267x; 1.0432x over previous
//
#include <hip/hip_runtime.h>
#include <hip/hip_bf16.h>
#include <stdint.h>

#define NR 8192   // rows (N)
#define ND 1024   // feature dim (D)

typedef __attribute__((ext_vector_type(8))) short bf16x8;  // 8 bf16 = 4 VGPR
typedef __attribute__((ext_vector_type(4))) float f32x4;   // MFMA C/D
typedef __attribute__((ext_vector_type(8))) unsigned short u16x8;

static __device__ __forceinline__ uint16_t f2bf(float f) {
  union { __hip_bfloat16 h; uint16_t u; } cv;
  cv.h = __float2bfloat16(f);
  return cv.u;
}
static __device__ __forceinline__ float bf2f(uint16_t u) {
  union { uint32_t i; float f; } cv;
  cv.i = ((uint32_t)u) << 16;
  return cv.f;
}

// ---------------- kernel 1: row L2 norm -> normalized bf16 ----------------
__global__ void k_norm(const float* __restrict__ X, uint16_t* __restrict__ Xn) {
  const int row = blockIdx.x;
  const int t = threadIdx.x;                    // 256 threads, 4 floats each
  const float4 v = reinterpret_cast<const float4*>(X + (size_t)row * ND)[t];
  float ss = v.x * v.x + v.y * v.y + v.z * v.z + v.w * v.w;
#pragma unroll
  for (int m = 1; m < 64; m <<= 1) ss += __shfl_xor(ss, m, 64);
  __shared__ float sred[4];
  if ((t & 63) == 0) sred[t >> 6] = ss;
  __syncthreads();
  const float tot = sred[0] + sred[1] + sred[2] + sred[3];
  const float inv = 1.0f / fmaxf(sqrtf(tot), 1e-12f);
  ushort4 o;
  o.x = f2bf(v.x * inv); o.y = f2bf(v.y * inv);
  o.z = f2bf(v.z * inv); o.w = f2bf(v.w * inv);
  reinterpret_cast<ushort4*>(Xn + (size_t)row * ND)[t] = o;
}

// ------------- kernel 1b: feats [NR][ND] f32 -> featsT [ND][NR] bf16 -------------
__global__ void k_transpose(const float* __restrict__ X, uint16_t* __restrict__ XT) {
  __shared__ uint16_t tile[32][33];
  const int ntr = NR / 32;                     // 256 row-tiles
  const int bx = blockIdx.x % ntr;             // row-tile of X
  const int by = blockIdx.x / ntr;             // col(dim)-tile of X
  const int r0 = bx * 32, d0 = by * 32;
  const int t = threadIdx.x;                   // 256
  const int rr = t >> 3, cc = (t & 7) * 4;
  const float4 v = *reinterpret_cast<const float4*>(&X[(size_t)(r0 + rr) * ND + d0 + cc]);
  tile[cc + 0][rr] = f2bf(v.x);
  tile[cc + 1][rr] = f2bf(v.y);
  tile[cc + 2][rr] = f2bf(v.z);
  tile[cc + 3][rr] = f2bf(v.w);
  __syncthreads();
  ushort4 o;
  o.x = tile[rr][cc + 0]; o.y = tile[rr][cc + 1];
  o.z = tile[rr][cc + 2]; o.w = tile[rr][cc + 3];
  *reinterpret_cast<ushort4*>(&XT[(size_t)(d0 + rr) * NR + r0 + cc]) = o;
}

// ---------------- 16-MFMA cluster (one C-quadrant x K=64) ----------------
template <int MH, int NH>
static __device__ __forceinline__ void mfma16(f32x4 (&acc)[8][4],
                                              const bf16x8 (&a_)[4][2],
                                              const bf16x8 (&b_)[2][2]) {
  __builtin_amdgcn_s_setprio(1);
#pragma unroll
  for (int kk = 0; kk < 2; ++kk)
#pragma unroll
    for (int m4 = 0; m4 < 4; ++m4)
#pragma unroll
      for (int n2 = 0; n2 < 2; ++n2)
        acc[MH * 4 + m4][NH * 2 + n2] = __builtin_amdgcn_mfma_f32_16x16x32_bf16(
            a_[m4][kk], b_[n2][kk], acc[MH * 4 + m4][NH * 2 + n2], 0, 0, 0);
  __builtin_amdgcn_s_setprio(0);
}

#define BAR()  __builtin_amdgcn_s_barrier()
#define LGKM() asm volatile("s_waitcnt lgkmcnt(0)" ::: "memory")
#define VMW()  asm volatile("s_waitcnt vmcnt(4)" ::: "memory")

// ---------------- 256x256 8-phase BT GEMM core ----------------
// C[m][n] = sum_k A[m][k]*B[n][k]
// EPI==0: sims epilogue (exp, diag 0, bf16 E main+mirror tile, row/col partials)
// EPI==1: plain fp32 store
// LDS map (bytes): dbuf d in {0,1}: d*65536 ; A half h: +h*16384 ; B: +32768+h*16384
// half-tile = [128 rows][64 k] bf16 rows of 128B, st_16x32 swizzle byte^=((byte>>9)&1)<<5
template <int EPI, int NKT>
static __device__ __forceinline__ void gemm8_core(
    char* sm,
    const uint16_t* __restrict__ A, int lda,
    const uint16_t* __restrict__ B, int ldb,
    int row0, int col0,
    float* __restrict__ C, int ldc,
    uint16_t* __restrict__ Eo, float* __restrict__ partials, int rb, int cb) {
  const int tid = threadIdx.x;
  const int wid = tid >> 6;
  const int lane = tid & 63;
  const int wr = wid >> 2;            // 0..1  (M wave)
  const int wc = wid & 3;             // 0..3  (N wave)
  const int flane = lane & 15;
  const int kbyte = (lane >> 4) * 16;                 // 16B k-chunk per lane group
  const int sbit = (flane >> 2) & 1;                  // swizzle bit for reads
  const int LOFF = flane * 128 + (kbyte ^ (sbit << 5));

  // staging source geometry (inverse-swizzled global source, linear LDS dest)
  const int colb = ((tid & 7) * 16) ^ (((tid >> 5) & 1) << 5);
  const int r0s = tid >> 3;           // row for load c=0; c=1 adds 64

  const char* const Abyte = (const char*)A + (size_t)row0 * lda * 2;
  const char* const Bbyte = (const char*)B + (size_t)col0 * ldb * 2;

  f32x4 acc[8][4] = {};
  bf16x8 a_[4][2], b_[2][2];

  auto stage = [&](int d, int isB, int h, int t) {
    const char* gb = isB ? Bbyte : Abyte;
    const int ld2 = (isB ? ldb : lda) * 2;
    const char* g0 = gb + (size_t)(h * 128 + r0s) * ld2 + t * 128 + colb;
    const char* g1 = g0 + (size_t)64 * ld2;
    char* l0 = sm + d * 65536 + isB * 32768 + h * 16384 + (wid << 10);
    __builtin_amdgcn_global_load_lds((const __attribute__((address_space(1))) void*)g0,
                                     (__attribute__((address_space(3))) void*)l0, 16, 0, 0);
    __builtin_amdgcn_global_load_lds((const __attribute__((address_space(1))) void*)g1,
                                     (__attribute__((address_space(3))) void*)(l0 + 8192), 16, 0, 0);
  };
  auto rdA = [&](int d, int mbase) {  // a_[m4][kk] for rows (mbase+m4)*16+flane of wave's half
#pragma unroll
    for (int m4 = 0; m4 < 4; ++m4)
#pragma unroll
      for (int kk = 0; kk < 2; ++kk)
        a_[m4][kk] = *(const bf16x8*)(sm + d * 65536 + wr * 16384 +
                                      (mbase + m4) * 2048 + kk * 64 + LOFF);
  };
  auto rdB = [&](int d, int nbase) {
#pragma unroll
    for (int n2 = 0; n2 < 2; ++n2)
#pragma unroll
      for (int kk = 0; kk < 2; ++kk)
        b_[n2][kk] = *(const bf16x8*)(sm + d * 65536 + 32768 + (wc >> 1) * 16384 +
                                      (wc & 1) * 8192 + (nbase + n2) * 2048 + kk * 64 + LOFF);
  };

  // prologue: d0 full K-tile 0; d1 A-halves of K-tile 1
  stage(0, 0, 0, 0); stage(0, 0, 1, 0); stage(0, 1, 0, 0); stage(0, 1, 1, 0);
  stage(1, 0, 0, 1); stage(1, 0, 1, 1);
  VMW();      // d0 landed (allow d1.A outstanding)
  BAR();

  const int niter = NKT / 2;
  for (int i = 0; i < niter; ++i) {
    const int t0 = 2 * i, t1 = 2 * i + 1;
    // Ph1: quadrant (0,0) of t0 ; stage d1.B(t1)
    rdA(0, 0); rdB(0, 0);
    stage(1, 1, 0, t1); stage(1, 1, 1, t1);
    BAR(); LGKM(); mfma16<0, 0>(acc, a_, b_); BAR();
    // Ph2: (0,1)
    rdB(0, 2);
    BAR(); LGKM(); mfma16<0, 1>(acc, a_, b_); BAR();
    // Ph3: (1,1)
    rdA(0, 4);
    BAR(); LGKM(); mfma16<1, 1>(acc, a_, b_); BAR();
    // Ph4: (1,0) ; stage d0.A(t0+2) ; vmcnt
    rdB(0, 0);
    if (t0 + 2 < NKT) { stage(0, 0, 0, t0 + 2); stage(0, 0, 1, t0 + 2); }
    BAR(); LGKM(); mfma16<1, 0>(acc, a_, b_); VMW(); BAR();
    // Ph5: quadrant (0,0) of t1 ; stage d0.B(t0+2)
    rdA(1, 0); rdB(1, 0);
    if (t0 + 2 < NKT) { stage(0, 1, 0, t0 + 2); stage(0, 1, 1, t0 + 2); }
    BAR(); LGKM(); mfma16<0, 0>(acc, a_, b_); BAR();
    // Ph6: (0,1)
    rdB(1, 2);
    BAR(); LGKM(); mfma16<0, 1>(acc, a_, b_); BAR();
    // Ph7: (1,1)
    rdA(1, 4);
    BAR(); LGKM(); mfma16<1, 1>(acc, a_, b_); BAR();
    // Ph8: (1,0) ; stage d1.A(t1+2) ; vmcnt
    rdB(1, 0);
    if (t1 + 2 < NKT) { stage(1, 0, 0, t1 + 2); stage(1, 0, 1, t1 + 2); }
    BAR(); LGKM(); mfma16<1, 0>(acc, a_, b_); VMW(); BAR();
  }

  const int e0 = (lane >> 4) * 4;   // C/D: row=(lane>>4)*4+e, col=lane&15

  if constexpr (EPI == 0) {
    const bool diag = (rb == cb);
    float rp[8][4] = {};   // [m][e] row partials
    float rpT[4] = {};     // [n]    col partials
#pragma unroll
    for (int m = 0; m < 8; ++m) {
      const int growb = row0 + wr * 128 + m * 16 + e0;
#pragma unroll
      for (int n = 0; n < 4; ++n) {
        const int gcol = col0 + wc * 64 + n * 16 + flane;
        ushort4 mpack;
#pragma unroll
        for (int e = 0; e < 4; ++e) {
          const int grow = growb + e;
          const float ev = (grow == gcol) ? 0.0f : __expf(acc[m][n][e]);
          const uint16_t eb = f2bf(ev);
          const float evr = bf2f(eb);     // sum the ROUNDED value (rows sum to 1)
          Eo[(size_t)grow * NR + gcol] = eb;
          rp[m][e] += evr;
          rpT[n] += evr;
          ((uint16_t*)&mpack)[e] = eb;
        }
        if (!diag)
          *reinterpret_cast<ushort4*>(&Eo[(size_t)gcol * NR + growb]) = mpack;
      }
    }
#pragma unroll
    for (int msk = 1; msk <= 8; msk <<= 1)
#pragma unroll
      for (int m = 0; m < 8; ++m)
#pragma unroll
        for (int e = 0; e < 4; ++e) rp[m][e] += __shfl_xor(rp[m][e], msk, 64);
#pragma unroll
    for (int msk = 16; msk <= 32; msk <<= 1)
#pragma unroll
      for (int n = 0; n < 4; ++n) rpT[n] += __shfl_xor(rpT[n], msk, 64);

    float* sRow = (float*)sm;            // [4][256]
    float* sCol = (float*)(sm + 4096);   // [2][256]
    __syncthreads();
    if (flane == 0) {
#pragma unroll
      for (int m = 0; m < 8; ++m)
#pragma unroll
        for (int e = 0; e < 4; ++e)
          sRow[wc * 256 + wr * 128 + m * 16 + e0 + e] = rp[m][e];
    }
    if (lane < 16) {
#pragma unroll
      for (int n = 0; n < 4; ++n) sCol[wr * 256 + wc * 64 + n * 16 + lane] = rpT[n];
    }
    __syncthreads();
    if (tid < 256) {
      partials[(size_t)cb * NR + row0 + tid] =
          sRow[tid] + sRow[256 + tid] + sRow[512 + tid] + sRow[768 + tid];
      if (!diag)
        partials[(size_t)rb * NR + col0 + tid] = sCol[tid] + sCol[256 + tid];
    }
  } else {
#pragma unroll
    for (int m = 0; m < 8; ++m)
#pragma unroll
      for (int n = 0; n < 4; ++n)
#pragma unroll
        for (int e = 0; e < 4; ++e)
          C[(size_t)(row0 + wr * 128 + m * 16 + e0 + e) * ldc +
            col0 + wc * 64 + n * 16 + flane] = acc[m][n][e];
  }
}

// sims GEMM over upper triangle (rb<=cb), 32x32 tiles of 256, XCD-swizzled
__global__ __launch_bounds__(512, 2) void k_gemm_sym8(
    const uint16_t* __restrict__ Xn, uint16_t* __restrict__ E,
    float* __restrict__ partials) {
  extern __shared__ char smem[];
  const int nwg = gridDim.x;            // 528 = 8*66
  const int cpx = nwg >> 3;
  const int b = blockIdx.x;
  const int swz = (b & 7) * cpx + (b >> 3);
  int rem = swz, rb = 0;
  while (rem >= 32 - rb) { rem -= 32 - rb; ++rb; }
  const int cb = rb + rem;
  gemm8_core<0, 16>(smem, Xn, ND, Xn, ND, rb * 256, cb * 256,
                    nullptr, 0, E, partials, rb, cb);
}

// PV GEMM: out = E(bf16) . X ; split-K x2, fp32 partials
__global__ __launch_bounds__(512, 2) void k_gemm_pv8(
    const uint16_t* __restrict__ E, const uint16_t* __restrict__ XT,
    float* __restrict__ P) {
  extern __shared__ char smem[];
  const int b = blockIdx.x;             // 256 = 8*32
  const int swz = (b & 7) * 32 + (b >> 3);
  const int s = swz >> 7;               // K split
  const int t = swz & 127;
  const int by = t >> 2, bx = t & 3;    // 32 x 4 tiles
  gemm8_core<1, 64>(smem, E + (size_t)s * 4096, NR, XT + (size_t)s * 4096, NR,
                    by * 256, bx * 256, P + (size_t)s * NR * ND, ND,
                    nullptr, nullptr, 0, 0);
}

// ---------------- rowsum: reduce 32 column-block partials ----------------
__global__ void k_rowsum(const float* __restrict__ partials, float* __restrict__ rowsum,
                         int ncb) {
  const int r = blockIdx.x * blockDim.x + threadIdx.x;  // 8192 threads
  float s = 0.0f;
  for (int cb = 0; cb < ncb; ++cb) s += partials[(size_t)cb * NR + r];
  rowsum[r] = s;
}

// ------- fixup: out = (P0 + P1) / rowsum -------
__global__ void k_fixup(const float4* __restrict__ P0, const float4* __restrict__ P1,
                        const float* __restrict__ rowsum, float4* __restrict__ out) {
  const size_t i = (size_t)blockIdx.x * blockDim.x + threadIdx.x;  // float4 units
  const int row = (int)(i >> 8);                                   // /(ND/4)
  const float inv = 1.0f / rowsum[row];
  const float4 a = P0[i], b = P1[i];
  float4 o;
  o.x = (a.x + b.x) * inv; o.y = (a.y + b.y) * inv;
  o.z = (a.z + b.z) * inv; o.w = (a.w + b.w) * inv;
  out[i] = o;
}

// ------- scale: attn(fp32, d_out) = E(bf16) / rowsum -------
__global__ void k_scale(const uint16_t* __restrict__ E, const float* __restrict__ rowsum,
                        float* __restrict__ attn) {
  const size_t total = (size_t)NR * NR / 8;
  for (size_t i = (size_t)blockIdx.x * blockDim.x + threadIdx.x; i < total;
       i += (size_t)gridDim.x * blockDim.x) {
    const int row = (int)(i >> 10);     // (i*8)/8192
    const float inv = 1.0f / rowsum[row];
    const u16x8 e = reinterpret_cast<const u16x8*>(E)[i];
    float4 o0, o1;
    o0.x = bf2f(e[0]) * inv; o0.y = bf2f(e[1]) * inv;
    o0.z = bf2f(e[2]) * inv; o0.w = bf2f(e[3]) * inv;
    o1.x = bf2f(e[4]) * inv; o1.y = bf2f(e[5]) * inv;
    o1.z = bf2f(e[6]) * inv; o1.w = bf2f(e[7]) * inv;
    reinterpret_cast<float4*>(attn)[2 * i + 0] = o0;
    reinterpret_cast<float4*>(attn)[2 * i + 1] = o1;
  }
}

extern "C" void kernel_launch(void* const* d_in, const int* in_sizes, int n_in,
                              void* d_out, int out_size, void* d_ws, size_t ws_size,
                              hipStream_t stream) {
  const float* X = (const float*)d_in[0];          // [8192][1024] fp32
  float* out = (float*)d_out;                       // [8192][1024] fp32
  float* attn = out + (size_t)NR * ND;              // [8192][8192] fp32

  char* ws = (char*)d_ws;
  const size_t off_Xn   = 0;                                  // 16 MB bf16 normalized
  const size_t off_XT   = off_Xn + (size_t)NR * ND * 2;       // 16 MB bf16 feats^T
  const size_t off_E    = off_XT + (size_t)ND * NR * 2;       // 128 MB bf16 unscaled exp
  const size_t off_part = off_E + (size_t)NR * NR * 2;        // 2 MB partials
  const size_t off_rs   = off_part + (size_t)64 * NR * 4;     // 32 KB rowsum
  const size_t needed   = off_rs + (size_t)NR * 4;
  if (ws_size < needed) return;

  uint16_t* Xn  = (uint16_t*)(ws + off_Xn);
  uint16_t* XT  = (uint16_t*)(ws + off_XT);
  uint16_t* E   = (uint16_t*)(ws + off_E);
  float* partials = (float*)(ws + off_part);
  float* rowsum   = (float*)(ws + off_rs);

  // PV split-K partials use the (not yet written) attn region of d_out as scratch
  float* P = attn;

  hipFuncSetAttribute((const void*)k_gemm_sym8,
                      hipFuncAttributeMaxDynamicSharedMemorySize, 131072);
  hipFuncSetAttribute((const void*)k_gemm_pv8,
                      hipFuncAttributeMaxDynamicSharedMemorySize, 131072);

  k_norm<<<NR, 256, 0, stream>>>(X, Xn);
  k_transpose<<<(NR / 32) * (ND / 32), 256, 0, stream>>>(X, XT);
  k_gemm_sym8<<<528, 512, 131072, stream>>>(Xn, E, partials);
  k_rowsum<<<NR / 256, 256, 0, stream>>>(partials, rowsum, 32);
  k_gemm_pv8<<<256, 512, 131072, stream>>>(E, XT, P);
  k_fixup<<<NR * ND / 4 / 256, 256, 0, stream>>>(
      (const float4*)P, (const float4*)(P + (size_t)NR * ND), rowsum, (float4*)out);
  k_scale<<<2048, 256, 0, stream>>>(E, rowsum, attn);
}